// Round 17
// baseline (145.712 us; speedup 1.0000x reference)
//
#include <hip/hip_runtime.h>
#include <hip/hip_bf16.h>
#include <math.h>

typedef __bf16 bf16;
typedef bf16  bf16x8 __attribute__((ext_vector_type(8)));
typedef bf16  bf16x4 __attribute__((ext_vector_type(4)));
typedef float f32x4  __attribute__((ext_vector_type(4)));
typedef float f32x16 __attribute__((ext_vector_type(16)));

#define B_   4
#define N_   2048
#define CH_  512
#define H_   8
#define D_   64
#define HID_ 512

__device__ __forceinline__ f32x4 mfma16(bf16x8 a, bf16x8 b, f32x4 c) {
    return __builtin_amdgcn_mfma_f32_16x16x32_bf16(a, b, c, 0, 0, 0);
}
__device__ __forceinline__ f32x16 mfma32(bf16x8 a, bf16x8 b, f32x16 c) {
    return __builtin_amdgcn_mfma_f32_32x32x16_bf16(a, b, c, 0, 0, 0);
}

#define GLL(src, dst) __builtin_amdgcn_global_load_lds( \
        (const __attribute__((address_space(1))) unsigned int*)(src), \
        (__attribute__((address_space(3))) unsigned int*)(dst), 16, 0, 0)

// ---------------- prep: f32 -> bf16 for x, w_qkv, w_out ----------------
__global__ __launch_bounds__(256) void prep_k(
    const float* __restrict__ x, const float* __restrict__ wq, const float* __restrict__ wo,
    bf16* __restrict__ xb, bf16* __restrict__ wqb, bf16* __restrict__ wob)
{
    const int NX = 4194304 / 4, NQ = 786432 / 4, NO = 262144 / 4;   // quads
    const int total = NX + NQ + NO;
    for (int idx = blockIdx.x * 256 + threadIdx.x; idx < total; idx += gridDim.x * 256) {
        const float4* src; bf16* dst; int off;
        if (idx < NX)           { src = (const float4*)x;  dst = xb;  off = idx; }
        else if (idx < NX + NQ) { src = (const float4*)wq; dst = wqb; off = idx - NX; }
        else                    { src = (const float4*)wo; dst = wob; off = idx - NX - NQ; }
        float4 v = src[off];
        bf16x4 o = { (bf16)v.x, (bf16)v.y, (bf16)v.z, (bf16)v.w };
        *reinterpret_cast<bf16x4*>(dst + (size_t)off * 4) = o;
    }
}

// ---------------- rope table: cos/sin[pos][d/2], 2048 x 32 ----------------
__global__ void rope_table_k(float* __restrict__ cosT, float* __restrict__ sinT) {
    int idx = blockIdx.x * 256 + threadIdx.x;   // 65536 = 2048*32
    int pos = idx >> 5, fi = idx & 31;
    double inv = pow(10000.0, -(double)(2 * fi) / 64.0);
    double ang = (double)pos * inv;
    cosT[idx] = (float)cos(ang);
    sinT[idx] = (float)sin(ang);
}

// ---------------- QKV GEMM (bf16, GLL-staged) + scale + RoPE ----------------
__global__ __launch_bounds__(256) void qkv_rope_k(
    const bf16* __restrict__ xb, const bf16* __restrict__ wb,
    const float* __restrict__ cosT, const float* __restrict__ sinT,
    bf16* __restrict__ Qb, bf16* __restrict__ Kb, bf16* __restrict__ Vt)
{
    __shared__ __align__(16) unsigned char Xs[2][16384];
    __shared__ __align__(16) unsigned char Ws[2][16384];
    const int tid = threadIdx.x, lane = tid & 63, wid = tid >> 6;
    const int wr = wid >> 1, wc = wid & 1;
    const int m0 = blockIdx.x * 128, n0 = blockIdx.y * 128;
    const int l15 = lane & 15, l4 = lane >> 4;

    const unsigned scol = ((lane & 7) * 16) ^ ((lane >> 3) << 4);
    const char* ag = (const char*)xb + (size_t)(m0 + wid * 32 + (lane >> 3)) * 1024 + scol;
    const char* bg = (const char*)wb + (size_t)(n0 + wid * 32 + (lane >> 3)) * 1024 + scol;

#define QSTAGE(buf, kt) do { \
        _Pragma("unroll") \
        for (int g = 0; g < 4; ++g) { \
            GLL(ag + (size_t)(kt) * 128 + (size_t)g * 8192, &Xs[buf][wid * 4096 + g * 1024]); \
            GLL(bg + (size_t)(kt) * 128 + (size_t)g * 8192, &Ws[buf][wid * 4096 + g * 1024]); \
        } \
    } while (0)

    f32x4 acc[4][4] = {};

    QSTAGE(0, 0);
    __syncthreads();

    for (int kt = 0; kt < 8; ++kt) {
        const int cur = kt & 1;
        if (kt < 7) QSTAGE(cur ^ 1, kt + 1);
#pragma unroll
        for (int ks = 0; ks < 2; ++ks) {
            bf16x8 a[4], bb[4];
#pragma unroll
            for (int mf = 0; mf < 4; ++mf) {
                const int row = wr * 64 + mf * 16 + l15;
                a[mf] = *reinterpret_cast<const bf16x8*>(
                    &Xs[cur][row * 128 + ((ks * 64 + l4 * 16) ^ ((l15 & 7) << 4))]);
            }
#pragma unroll
            for (int nf = 0; nf < 4; ++nf) {
                const int row = wc * 64 + nf * 16 + l15;
                bb[nf] = *reinterpret_cast<const bf16x8*>(
                    &Ws[cur][row * 128 + ((ks * 64 + l4 * 16) ^ ((l15 & 7) << 4))]);
            }
#pragma unroll
            for (int mf = 0; mf < 4; ++mf)
#pragma unroll
                for (int nf = 0; nf < 4; ++nf)
                    acc[mf][nf] = mfma16(a[mf], bb[nf], acc[mf][nf]);
        }
        __syncthreads();
    }

    // epilogue: RoPE + scatter
#pragma unroll
    for (int nf = 0; nf < 4; ++nf) {
        const int col = n0 + wc * 64 + nf * 16 + l15;
        const int sec = col >> 9;            // 0=Q 1=K 2=V (uniform per block)
        const int cc = col & 511;
        const int hh = cc >> 6, dd = cc & 63;
        if (sec == 2) {
#pragma unroll
            for (int mf = 0; mf < 4; ++mf) {
                const int pos0 = m0 + wr * 64 + mf * 16 + l4 * 4;
                const int bb_ = pos0 >> 11, pos = pos0 & 2047;
                bf16x4 pk = { (bf16)acc[mf][nf][0], (bf16)acc[mf][nf][1],
                              (bf16)acc[mf][nf][2], (bf16)acc[mf][nf][3] };
                *reinterpret_cast<bf16x4*>(
                    Vt + ((size_t)(bb_ * H_ + hh) * D_ + dd) * N_ + pos) = pk;
            }
        } else {
            const float sgn = (dd & 1) ? 1.f : -1.f;
#pragma unroll
            for (int mf = 0; mf < 4; ++mf) {
#pragma unroll
                for (int i = 0; i < 4; ++i) {
                    const int row = m0 + wr * 64 + mf * 16 + l4 * 4 + i;
                    const int bb_ = row >> 11, pos = row & 2047;
                    const float v = acc[mf][nf][i];
                    const float v2 = __shfl_xor(v, 1);   // partner d^1
                    const size_t dst = ((size_t)((bb_ * H_ + hh) * N_ + pos)) * D_ + dd;
                    const float c = cosT[pos * 32 + (dd >> 1)];
                    const float s = sinT[pos * 32 + (dd >> 1)];
                    const float r = v * c + sgn * v2 * s;
                    if (sec == 0) Qb[dst] = (bf16)(r * 0.125f);
                    else          Kb[dst] = (bf16)r;
                }
            }
        }
    }
}

// ---------------- flash attention v17: T15 two-state pipeline ----------------
// R14 base (1024 blocks XCD-swizzled, 2 waves x 32 q-rows, KVBLK=64, swapped
// QK^T mfma32, no max-tracking, P through per-wave LDS, bias reg-dbuf, GLL
// dbuf staging) with QK^T pulled ONE ITERATION EARLY: iter t computes
// QK^T(t+1)->sB adjacent to softmax(t) (reads sA only) -> independent MFMA
// and VALU streams the scheduler can interleave (m114: separate pipes).
// K is therefore staged at t+2 (dbuf still safe: tile t's K-reads all
// complete before sync(t-1); the t+2 write lands after it). V/bias at t+1
// as before. Extra barrier after pre-loop QK^T(0) closes the only new
// cross-wave hazard (wave A's STAGE_K(2) vs wave B's in-flight QK^T(0)).
#define KRD2(kt2,kc) (((kt2)*32 + l31)*128 + (((kc)*32 + l5*16) ^ (l7<<4)))
#define VRD2(dt,kt)  (((dt)*32 + l31)*128 + (((kt)*32 + l5*16) ^ (l7<<4)))
#define PRD2(kt)     (wid*4096 + l31*128 + (((kt)*32 + l5*16) ^ (l7<<4)))
#define PST2(kt2,r2) (wid*4096 + l31*128 + (((kt2)*64 + (r2)*16 + l5*8) ^ (l7<<4)))

__global__ __launch_bounds__(128, 2) void attn_k(
    const bf16* __restrict__ Qb, const bf16* __restrict__ Kb, const bf16* __restrict__ Vt,
    const float* __restrict__ bias, bf16* __restrict__ AO)
{
    __shared__ __align__(16) unsigned char KsB[2][8192];
    __shared__ __align__(16) unsigned char VsB[2][8192];
    __shared__ __align__(16) unsigned char PwB[2][4096];

    const int tid = threadIdx.x, lane = tid & 63, wid = tid >> 6;
    const int l31 = lane & 31, l5 = lane >> 5, l7 = lane & 7;
    const int id = blockIdx.x;
    const int xcd = id & 7, j = id >> 3;
    const int bh = xcd + 8 * (j >> 5);
    const int qt = j & 31;
    const int b = bh >> 3, h = bh & 7;
    const int q0 = qt * 64 + wid * 32;
    const size_t bhoff = (size_t)bh * N_ * D_;

    bf16x8 qreg[4];
#pragma unroll
    for (int kc = 0; kc < 4; ++kc)
        qreg[kc] = *reinterpret_cast<const bf16x8*>(
            Qb + bhoff + (size_t)(q0 + l31) * D_ + kc * 16 + l5 * 8);

    const unsigned scol = ((lane & 7) * 16) ^ ((lane >> 3) << 4);
    const char* kg = (const char*)(Kb + bhoff) + (size_t)(wid * 32 + (lane >> 3)) * 128 + scol;
    const char* vg = (const char*)(Vt + bhoff) + (size_t)(wid * 32 + (lane >> 3)) * (N_ * 2) + scol;

    const float* bp = bias + ((size_t)h * N_ + (q0 + l31)) * N_ + l5 * 4;

    unsigned char* pwD = &PwB[0][0];

#define STAGE_K(buf, t) do { \
        GLL(kg + (size_t)(t) * 8192,            &KsB[buf][wid * 4096]); \
        GLL(kg + (size_t)(t) * 8192 + 1024,     &KsB[buf][wid * 4096 + 1024]); \
        GLL(kg + (size_t)(t) * 8192 + 2048,     &KsB[buf][wid * 4096 + 2048]); \
        GLL(kg + (size_t)(t) * 8192 + 3072,     &KsB[buf][wid * 4096 + 3072]); \
    } while (0)

#define STAGE_V(buf, t) do { \
        GLL(vg + (size_t)(t) * 128,             &VsB[buf][wid * 4096]); \
        GLL(vg + (size_t)(t) * 128 + 32768,     &VsB[buf][wid * 4096 + 1024]); \
        GLL(vg + (size_t)(t) * 128 + 65536,     &VsB[buf][wid * 4096 + 2048]); \
        GLL(vg + (size_t)(t) * 128 + 98304,     &VsB[buf][wid * 4096 + 3072]); \
    } while (0)

    f32x16 o[2] = {};
    f32x16 sA[2] = {};
    float lp = 0.f;
    f32x4 bc[2][4], bn[2][4];

    // ---- prologue: stage K0, K1, V0; bias(0) ----
    STAGE_K(0, 0);
    STAGE_K(1, 1);
    STAGE_V(0, 0);
#pragma unroll
    for (int kt2 = 0; kt2 < 2; ++kt2)
#pragma unroll
        for (int r2 = 0; r2 < 4; ++r2)
            bc[kt2][r2] = *reinterpret_cast<const f32x4*>(bp + kt2 * 32 + r2 * 8);
    __syncthreads();

    // QK^T(0) -> sA
    {
        const unsigned char* ksC = &KsB[0][0];
        __builtin_amdgcn_s_setprio(1);
#pragma unroll
        for (int kt2 = 0; kt2 < 2; ++kt2)
#pragma unroll
            for (int kc = 0; kc < 4; ++kc) {
                bf16x8 kf = *reinterpret_cast<const bf16x8*>(ksC + KRD2(kt2, kc));
                sA[kt2] = mfma32(kf, qreg[kc], sA[kt2]);
            }
        __builtin_amdgcn_s_setprio(0);
    }
    __syncthreads();   // all waves' QK^T(0) reads drained before STAGE_K(2) writes KsB[0]

#pragma unroll 2
    for (int kb = 0; kb < 32; ++kb) {
        const int cur = kb & 1;
        if (kb < 30) STAGE_K(cur, kb + 2);
        if (kb < 31) {
            STAGE_V(cur ^ 1, kb + 1);
#pragma unroll
            for (int kt2 = 0; kt2 < 2; ++kt2)
#pragma unroll
                for (int r2 = 0; r2 < 4; ++r2)
                    bn[kt2][r2] = *reinterpret_cast<const f32x4*>(
                        bp + (size_t)(kb + 1) * 64 + kt2 * 32 + r2 * 8);
        }

        // ---- QK^T(kb+1) -> sB : independent of softmax(kb) below ----
        f32x16 sB[2] = {};
        if (kb < 31) {
            const unsigned char* ksC = &KsB[cur ^ 1][0];
#pragma unroll
            for (int kt2 = 0; kt2 < 2; ++kt2)
#pragma unroll
                for (int kc = 0; kc < 4; ++kc) {
                    bf16x8 kf = *reinterpret_cast<const bf16x8*>(ksC + KRD2(kt2, kc));
                    sB[kt2] = mfma32(kf, qreg[kc], sB[kt2]);
                }
        }

        // ---- softmax(kb): p = exp(sA + bias) -> per-wave LDS ----
#pragma unroll
        for (int kt2 = 0; kt2 < 2; ++kt2) {
#pragma unroll
            for (int r2 = 0; r2 < 4; ++r2) {
                float p0 = __expf(sA[kt2][r2 * 4 + 0] + bc[kt2][r2][0]);
                float p1 = __expf(sA[kt2][r2 * 4 + 1] + bc[kt2][r2][1]);
                float p2 = __expf(sA[kt2][r2 * 4 + 2] + bc[kt2][r2][2]);
                float p3 = __expf(sA[kt2][r2 * 4 + 3] + bc[kt2][r2][3]);
                lp += (p0 + p1) + (p2 + p3);
                bf16x4 pk = { (bf16)p0, (bf16)p1, (bf16)p2, (bf16)p3 };
                *reinterpret_cast<bf16x4*>(pwD + PST2(kt2, r2)) = pk;
            }
        }

        // ---- PV(kb): O += P @ V ----
        const unsigned char* vsC = &VsB[cur][0];
        __builtin_amdgcn_s_setprio(1);
#pragma unroll
        for (int kt = 0; kt < 4; ++kt) {
            bf16x8 pa = *reinterpret_cast<const bf16x8*>(pwD + PRD2(kt));
#pragma unroll
            for (int dt = 0; dt < 2; ++dt) {
                bf16x8 vf = *reinterpret_cast<const bf16x8*>(vsC + VRD2(dt, kt));
                o[dt] = mfma32(pa, vf, o[dt]);
            }
        }
        __builtin_amdgcn_s_setprio(0);

        // ---- rotate 2-state + bias ----
        sA[0] = sB[0];
        sA[1] = sB[1];
#pragma unroll
        for (int kt2 = 0; kt2 < 2; ++kt2)
#pragma unroll
            for (int r2 = 0; r2 < 4; ++r2)
                bc[kt2][r2] = bn[kt2][r2];
        __syncthreads();
    }

    float tot = lp;
    tot += __shfl_xor(tot, 32);
    float rv[16];
#pragma unroll
    for (int reg = 0; reg < 16; ++reg) {
        const int qr = (reg & 3) + 8 * (reg >> 2) + 4 * l5;
        rv[reg] = 1.0f / __shfl(tot, qr);
    }
#pragma unroll
    for (int dt = 0; dt < 2; ++dt)
#pragma unroll
        for (int reg = 0; reg < 16; ++reg) {
            const int qr = (reg & 3) + 8 * (reg >> 2) + 4 * l5;
            AO[((size_t)(b * N_ + q0 + qr)) * HID_ + h * D_ + dt * 32 + l31] =
                (bf16)(o[dt][reg] * rv[reg]);
        }
}

// ---------------- out projection (bf16, GLL-staged): AO @ wob^T -> f32 ----------------
__global__ __launch_bounds__(256) void proj_k(
    const bf16* __restrict__ A, const bf16* __restrict__ wob, float* __restrict__ out)
{
    __shared__ __align__(16) unsigned char Xs[2][16384];
    __shared__ __align__(16) unsigned char Ws[2][16384];
    const int tid = threadIdx.x, lane = tid & 63, wid = tid >> 6;
    const int wr = wid >> 1, wc = wid & 1;
    const int m0 = blockIdx.x * 128, n0 = blockIdx.y * 128;
    const int l15 = lane & 15, l4 = lane >> 4;

    const unsigned scol = ((lane & 7) * 16) ^ ((lane >> 3) << 4);
    const char* ag = (const char*)A   + (size_t)(m0 + wid * 32 + (lane >> 3)) * 1024 + scol;
    const char* bg = (const char*)wob + (size_t)(n0 + wid * 32 + (lane >> 3)) * 1024 + scol;

#define PSTAGE(buf, kt) do { \
        _Pragma("unroll") \
        for (int g = 0; g < 4; ++g) { \
            GLL(ag + (size_t)(kt) * 128 + (size_t)g * 8192, &Xs[buf][wid * 4096 + g * 1024]); \
            GLL(bg + (size_t)(kt) * 128 + (size_t)g * 8192, &Ws[buf][wid * 4096 + g * 1024]); \
        } \
    } while (0)

    f32x4 acc[4][4] = {};

    PSTAGE(0, 0);
    __syncthreads();

    for (int kt = 0; kt < 8; ++kt) {
        const int cur = kt & 1;
        if (kt < 7) PSTAGE(cur ^ 1, kt + 1);
#pragma unroll
        for (int ks = 0; ks < 2; ++ks) {
            bf16x8 a[4], bb[4];
#pragma unroll
            for (int mf = 0; mf < 4; ++mf) {
                const int row = wr * 64 + mf * 16 + l15;
                a[mf] = *reinterpret_cast<const bf16x8*>(
                    &Xs[cur][row * 128 + ((ks * 64 + l4 * 16) ^ ((l15 & 7) << 4))]);
            }
#pragma unroll
            for (int nf = 0; nf < 4; ++nf) {
                const int row = wc * 64 + nf * 16 + l15;
                bb[nf] = *reinterpret_cast<const bf16x8*>(
                    &Ws[cur][row * 128 + ((ks * 64 + l4 * 16) ^ ((l15 & 7) << 4))]);
            }
#pragma unroll
            for (int mf = 0; mf < 4; ++mf)
#pragma unroll
                for (int nf = 0; nf < 4; ++nf)
                    acc[mf][nf] = mfma16(a[mf], bb[nf], acc[mf][nf]);
        }
        __syncthreads();
    }

#pragma unroll
    for (int nf = 0; nf < 4; ++nf) {
        const int col = n0 + wc * 64 + nf * 16 + l15;
#pragma unroll
        for (int mf = 0; mf < 4; ++mf) {
#pragma unroll
            for (int i = 0; i < 4; ++i) {
                const int row = m0 + wr * 64 + mf * 16 + l4 * 4 + i;
                out[(size_t)row * HID_ + col] = acc[mf][nf][i];
            }
        }
    }
}

extern "C" void kernel_launch(void* const* d_in, const int* in_sizes, int n_in,
                              void* d_out, int out_size, void* d_ws, size_t ws_size,
                              hipStream_t stream) {
    (void)in_sizes; (void)n_in; (void)out_size; (void)ws_size;
    const float* x     = (const float*)d_in[0];
    const float* bias  = (const float*)d_in[1];
    const float* w_qkv = (const float*)d_in[2];
    const float* w_out = (const float*)d_in[3];
    float* out = (float*)d_out;

    bf16* base = (bf16*)d_ws;
    bf16* Qb = base;                         // [4*8][2048][64]
    bf16* Kb = base + 4194304;               // [4*8][2048][64]
    bf16* Vt = base + 8388608;               // [4*8][64][2048] (transposed)
    bf16* AO = base + 12582912;              // [4][2048][512]; ALSO xb before attn
    bf16* xb = AO;                           // aliases AO (xb dead before attn writes)
    float* cosT = (float*)(base + 16777216); // [2048][32]
    float* sinT = cosT + 65536;
    bf16* wqb = (bf16*)(sinT + 65536);       // [1536][512]
    bf16* wob = wqb + 786432;                // [512][512]

    prep_k      <<<dim3(2560), 256, 0, stream>>>(x, w_qkv, w_out, xb, wqb, wob);
    rope_table_k<<<dim3(256), 256, 0, stream>>>(cosT, sinT);
    qkv_rope_k  <<<dim3(64, 12), 256, 0, stream>>>(xb, wqb, cosT, sinT, Qb, Kb, Vt);
    attn_k      <<<dim3(1024), 128, 0, stream>>>(Qb, Kb, Vt, bias, AO);
    proj_k      <<<dim3(64, 4), 256, 0, stream>>>(AO, wob, out);
}

// Round 18
// 131.013 us; speedup vs baseline: 1.1122x; 1.1122x over previous
//
#include <hip/hip_runtime.h>
#include <hip/hip_bf16.h>
#include <math.h>

typedef __bf16 bf16;
typedef bf16  bf16x8 __attribute__((ext_vector_type(8)));
typedef bf16  bf16x4 __attribute__((ext_vector_type(4)));
typedef float f32x4  __attribute__((ext_vector_type(4)));
typedef float f32x16 __attribute__((ext_vector_type(16)));

#define B_   4
#define N_   2048
#define CH_  512
#define H_   8
#define D_   64
#define HID_ 512

__device__ __forceinline__ f32x4 mfma16(bf16x8 a, bf16x8 b, f32x4 c) {
    return __builtin_amdgcn_mfma_f32_16x16x32_bf16(a, b, c, 0, 0, 0);
}
__device__ __forceinline__ f32x16 mfma32(bf16x8 a, bf16x8 b, f32x16 c) {
    return __builtin_amdgcn_mfma_f32_32x32x16_bf16(a, b, c, 0, 0, 0);
}

#define GLL(src, dst) __builtin_amdgcn_global_load_lds( \
        (const __attribute__((address_space(1))) unsigned int*)(src), \
        (__attribute__((address_space(3))) unsigned int*)(dst), 16, 0, 0)

// ---------------- prep: f32 -> bf16 for x, w_qkv, w_out ----------------
__global__ __launch_bounds__(256) void prep_k(
    const float* __restrict__ x, const float* __restrict__ wq, const float* __restrict__ wo,
    bf16* __restrict__ xb, bf16* __restrict__ wqb, bf16* __restrict__ wob)
{
    const int NX = 4194304 / 4, NQ = 786432 / 4, NO = 262144 / 4;   // quads
    const int total = NX + NQ + NO;
    for (int idx = blockIdx.x * 256 + threadIdx.x; idx < total; idx += gridDim.x * 256) {
        const float4* src; bf16* dst; int off;
        if (idx < NX)           { src = (const float4*)x;  dst = xb;  off = idx; }
        else if (idx < NX + NQ) { src = (const float4*)wq; dst = wqb; off = idx - NX; }
        else                    { src = (const float4*)wo; dst = wob; off = idx - NX - NQ; }
        float4 v = src[off];
        bf16x4 o = { (bf16)v.x, (bf16)v.y, (bf16)v.z, (bf16)v.w };
        *reinterpret_cast<bf16x4*>(dst + (size_t)off * 4) = o;
    }
}

// ---------------- rope table: cos/sin[pos][d/2], 2048 x 32 ----------------
__global__ void rope_table_k(float* __restrict__ cosT, float* __restrict__ sinT) {
    int idx = blockIdx.x * 256 + threadIdx.x;   // 65536 = 2048*32
    int pos = idx >> 5, fi = idx & 31;
    double inv = pow(10000.0, -(double)(2 * fi) / 64.0);
    double ang = (double)pos * inv;
    cosT[idx] = (float)cos(ang);
    sinT[idx] = (float)sin(ang);
}

// ---------------- QKV GEMM (bf16, GLL-staged) + scale + RoPE ----------------
__global__ __launch_bounds__(256) void qkv_rope_k(
    const bf16* __restrict__ xb, const bf16* __restrict__ wb,
    const float* __restrict__ cosT, const float* __restrict__ sinT,
    bf16* __restrict__ Qb, bf16* __restrict__ Kb, bf16* __restrict__ Vt)
{
    __shared__ __align__(16) unsigned char Xs[2][16384];
    __shared__ __align__(16) unsigned char Ws[2][16384];
    const int tid = threadIdx.x, lane = tid & 63, wid = tid >> 6;
    const int wr = wid >> 1, wc = wid & 1;
    const int m0 = blockIdx.x * 128, n0 = blockIdx.y * 128;
    const int l15 = lane & 15, l4 = lane >> 4;

    const unsigned scol = ((lane & 7) * 16) ^ ((lane >> 3) << 4);
    const char* ag = (const char*)xb + (size_t)(m0 + wid * 32 + (lane >> 3)) * 1024 + scol;
    const char* bg = (const char*)wb + (size_t)(n0 + wid * 32 + (lane >> 3)) * 1024 + scol;

#define QSTAGE(buf, kt) do { \
        _Pragma("unroll") \
        for (int g = 0; g < 4; ++g) { \
            GLL(ag + (size_t)(kt) * 128 + (size_t)g * 8192, &Xs[buf][wid * 4096 + g * 1024]); \
            GLL(bg + (size_t)(kt) * 128 + (size_t)g * 8192, &Ws[buf][wid * 4096 + g * 1024]); \
        } \
    } while (0)

    f32x4 acc[4][4] = {};

    QSTAGE(0, 0);
    __syncthreads();

    for (int kt = 0; kt < 8; ++kt) {
        const int cur = kt & 1;
        if (kt < 7) QSTAGE(cur ^ 1, kt + 1);
#pragma unroll
        for (int ks = 0; ks < 2; ++ks) {
            bf16x8 a[4], bb[4];
#pragma unroll
            for (int mf = 0; mf < 4; ++mf) {
                const int row = wr * 64 + mf * 16 + l15;
                a[mf] = *reinterpret_cast<const bf16x8*>(
                    &Xs[cur][row * 128 + ((ks * 64 + l4 * 16) ^ ((l15 & 7) << 4))]);
            }
#pragma unroll
            for (int nf = 0; nf < 4; ++nf) {
                const int row = wc * 64 + nf * 16 + l15;
                bb[nf] = *reinterpret_cast<const bf16x8*>(
                    &Ws[cur][row * 128 + ((ks * 64 + l4 * 16) ^ ((l15 & 7) << 4))]);
            }
#pragma unroll
            for (int mf = 0; mf < 4; ++mf)
#pragma unroll
                for (int nf = 0; nf < 4; ++nf)
                    acc[mf][nf] = mfma16(a[mf], bb[nf], acc[mf][nf]);
        }
        __syncthreads();
    }

    // epilogue: RoPE + scatter
#pragma unroll
    for (int nf = 0; nf < 4; ++nf) {
        const int col = n0 + wc * 64 + nf * 16 + l15;
        const int sec = col >> 9;            // 0=Q 1=K 2=V (uniform per block)
        const int cc = col & 511;
        const int hh = cc >> 6, dd = cc & 63;
        if (sec == 2) {
#pragma unroll
            for (int mf = 0; mf < 4; ++mf) {
                const int pos0 = m0 + wr * 64 + mf * 16 + l4 * 4;
                const int bb_ = pos0 >> 11, pos = pos0 & 2047;
                bf16x4 pk = { (bf16)acc[mf][nf][0], (bf16)acc[mf][nf][1],
                              (bf16)acc[mf][nf][2], (bf16)acc[mf][nf][3] };
                *reinterpret_cast<bf16x4*>(
                    Vt + ((size_t)(bb_ * H_ + hh) * D_ + dd) * N_ + pos) = pk;
            }
        } else {
            const float sgn = (dd & 1) ? 1.f : -1.f;
#pragma unroll
            for (int mf = 0; mf < 4; ++mf) {
#pragma unroll
                for (int i = 0; i < 4; ++i) {
                    const int row = m0 + wr * 64 + mf * 16 + l4 * 4 + i;
                    const int bb_ = row >> 11, pos = row & 2047;
                    const float v = acc[mf][nf][i];
                    const float v2 = __shfl_xor(v, 1);   // partner d^1
                    const size_t dst = ((size_t)((bb_ * H_ + hh) * N_ + pos)) * D_ + dd;
                    const float c = cosT[pos * 32 + (dd >> 1)];
                    const float s = sinT[pos * 32 + (dd >> 1)];
                    const float r = v * c + sgn * v2 * s;
                    if (sec == 0) Qb[dst] = (bf16)(r * 0.125f);
                    else          Kb[dst] = (bf16)r;
                }
            }
        }
    }
}

// ---------------- flash attention (best measured: ~105 us) ----------------
// 1024 blocks (XCD-swizzled), 2 waves x 32 q-rows, KVBLK=64, swapped QK^T
// (mfma32), no max-tracking, bias reg-dbuf, GLL dbuf staging, Vt.
#define KRD2(kt2,kc) (((kt2)*32 + l31)*128 + (((kc)*32 + l5*16) ^ (l7<<4)))
#define VRD2(dt,kt)  (((dt)*32 + l31)*128 + (((kt)*32 + l5*16) ^ (l7<<4)))
#define PRD2(kt)     (wid*4096 + l31*128 + (((kt)*32 + l5*16) ^ (l7<<4)))
#define PST2(kt2,r2) (wid*4096 + l31*128 + (((kt2)*64 + (r2)*16 + l5*8) ^ (l7<<4)))

__global__ __launch_bounds__(128, 2) void attn_k(
    const bf16* __restrict__ Qb, const bf16* __restrict__ Kb, const bf16* __restrict__ Vt,
    const float* __restrict__ bias, bf16* __restrict__ AO)
{
    __shared__ __align__(16) unsigned char KsB[2][8192];
    __shared__ __align__(16) unsigned char VsB[2][8192];
    __shared__ __align__(16) unsigned char PwB[2][4096];

    const int tid = threadIdx.x, lane = tid & 63, wid = tid >> 6;
    const int l31 = lane & 31, l5 = lane >> 5, l7 = lane & 7;
    const int id = blockIdx.x;
    const int xcd = id & 7, j = id >> 3;
    const int bh = xcd + 8 * (j >> 5);
    const int qt = j & 31;
    const int b = bh >> 3, h = bh & 7;
    const int q0 = qt * 64 + wid * 32;
    const size_t bhoff = (size_t)bh * N_ * D_;

    bf16x8 qreg[4];
#pragma unroll
    for (int kc = 0; kc < 4; ++kc)
        qreg[kc] = *reinterpret_cast<const bf16x8*>(
            Qb + bhoff + (size_t)(q0 + l31) * D_ + kc * 16 + l5 * 8);

    const unsigned scol = ((lane & 7) * 16) ^ ((lane >> 3) << 4);
    const char* kg = (const char*)(Kb + bhoff) + (size_t)(wid * 32 + (lane >> 3)) * 128 + scol;
    const char* vg = (const char*)(Vt + bhoff) + (size_t)(wid * 32 + (lane >> 3)) * (N_ * 2) + scol;

    const float* bp = bias + ((size_t)h * N_ + (q0 + l31)) * N_ + l5 * 4;

    unsigned char* pwD = &PwB[0][0];

#define STAGE(buf, t) do { \
        GLL(kg + (size_t)(t) * 8192,            &KsB[buf][wid * 4096]); \
        GLL(kg + (size_t)(t) * 8192 + 1024,     &KsB[buf][wid * 4096 + 1024]); \
        GLL(kg + (size_t)(t) * 8192 + 2048,     &KsB[buf][wid * 4096 + 2048]); \
        GLL(kg + (size_t)(t) * 8192 + 3072,     &KsB[buf][wid * 4096 + 3072]); \
        GLL(vg + (size_t)(t) * 128,             &VsB[buf][wid * 4096]); \
        GLL(vg + (size_t)(t) * 128 + 32768,     &VsB[buf][wid * 4096 + 1024]); \
        GLL(vg + (size_t)(t) * 128 + 65536,     &VsB[buf][wid * 4096 + 2048]); \
        GLL(vg + (size_t)(t) * 128 + 98304,     &VsB[buf][wid * 4096 + 3072]); \
    } while (0)

    f32x16 o[2] = {};
    float lp = 0.f;
    f32x4 bc[2][4], bn[2][4];

    STAGE(0, 0);
#pragma unroll
    for (int kt2 = 0; kt2 < 2; ++kt2)
#pragma unroll
        for (int r2 = 0; r2 < 4; ++r2)
            bc[kt2][r2] = *reinterpret_cast<const f32x4*>(bp + kt2 * 32 + r2 * 8);
    __syncthreads();

#pragma unroll 2
    for (int kb = 0; kb < 32; ++kb) {
        const int cur = kb & 1;
        if (kb < 31) {
            STAGE(cur ^ 1, kb + 1);
#pragma unroll
            for (int kt2 = 0; kt2 < 2; ++kt2)
#pragma unroll
                for (int r2 = 0; r2 < 4; ++r2)
                    bn[kt2][r2] = *reinterpret_cast<const f32x4*>(
                        bp + (size_t)(kb + 1) * 64 + kt2 * 32 + r2 * 8);
        }

        const unsigned char* ksC = &KsB[cur][0];
        f32x16 s[2] = {};
        __builtin_amdgcn_s_setprio(1);
#pragma unroll
        for (int kt2 = 0; kt2 < 2; ++kt2) {
#pragma unroll
            for (int kc = 0; kc < 4; ++kc) {
                bf16x8 kf = *reinterpret_cast<const bf16x8*>(ksC + KRD2(kt2, kc));
                s[kt2] = mfma32(kf, qreg[kc], s[kt2]);
            }
        }
        __builtin_amdgcn_s_setprio(0);

#pragma unroll
        for (int kt2 = 0; kt2 < 2; ++kt2) {
#pragma unroll
            for (int r2 = 0; r2 < 4; ++r2) {
                float p0 = __expf(s[kt2][r2 * 4 + 0] + bc[kt2][r2][0]);
                float p1 = __expf(s[kt2][r2 * 4 + 1] + bc[kt2][r2][1]);
                float p2 = __expf(s[kt2][r2 * 4 + 2] + bc[kt2][r2][2]);
                float p3 = __expf(s[kt2][r2 * 4 + 3] + bc[kt2][r2][3]);
                lp += (p0 + p1) + (p2 + p3);
                bf16x4 pk = { (bf16)p0, (bf16)p1, (bf16)p2, (bf16)p3 };
                *reinterpret_cast<bf16x4*>(pwD + PST2(kt2, r2)) = pk;
            }
        }

        const unsigned char* vsC = &VsB[cur][0];
        __builtin_amdgcn_s_setprio(1);
#pragma unroll
        for (int kt = 0; kt < 4; ++kt) {
            bf16x8 pa = *reinterpret_cast<const bf16x8*>(pwD + PRD2(kt));
#pragma unroll
            for (int dt = 0; dt < 2; ++dt) {
                bf16x8 vf = *reinterpret_cast<const bf16x8*>(vsC + VRD2(dt, kt));
                o[dt] = mfma32(pa, vf, o[dt]);
            }
        }
        __builtin_amdgcn_s_setprio(0);

#pragma unroll
        for (int kt2 = 0; kt2 < 2; ++kt2)
#pragma unroll
            for (int r2 = 0; r2 < 4; ++r2)
                bc[kt2][r2] = bn[kt2][r2];
        __syncthreads();
    }

    float tot = lp;
    tot += __shfl_xor(tot, 32);
    float rv[16];
#pragma unroll
    for (int reg = 0; reg < 16; ++reg) {
        const int qr = (reg & 3) + 8 * (reg >> 2) + 4 * l5;
        rv[reg] = 1.0f / __shfl(tot, qr);
    }
#pragma unroll
    for (int dt = 0; dt < 2; ++dt)
#pragma unroll
        for (int reg = 0; reg < 16; ++reg) {
            const int qr = (reg & 3) + 8 * (reg >> 2) + 4 * l5;
            AO[((size_t)(b * N_ + q0 + qr)) * HID_ + h * D_ + dt * 32 + l31] =
                (bf16)(o[dt][reg] * rv[reg]);
        }
}

// ---------------- out projection (bf16, GLL-staged): AO @ wob^T -> f32 ----------------
__global__ __launch_bounds__(256) void proj_k(
    const bf16* __restrict__ A, const bf16* __restrict__ wob, float* __restrict__ out)
{
    __shared__ __align__(16) unsigned char Xs[2][16384];
    __shared__ __align__(16) unsigned char Ws[2][16384];
    const int tid = threadIdx.x, lane = tid & 63, wid = tid >> 6;
    const int wr = wid >> 1, wc = wid & 1;
    const int m0 = blockIdx.x * 128, n0 = blockIdx.y * 128;
    const int l15 = lane & 15, l4 = lane >> 4;

    const unsigned scol = ((lane & 7) * 16) ^ ((lane >> 3) << 4);
    const char* ag = (const char*)A   + (size_t)(m0 + wid * 32 + (lane >> 3)) * 1024 + scol;
    const char* bg = (const char*)wob + (size_t)(n0 + wid * 32 + (lane >> 3)) * 1024 + scol;

#define PSTAGE(buf, kt) do { \
        _Pragma("unroll") \
        for (int g = 0; g < 4; ++g) { \
            GLL(ag + (size_t)(kt) * 128 + (size_t)g * 8192, &Xs[buf][wid * 4096 + g * 1024]); \
            GLL(bg + (size_t)(kt) * 128 + (size_t)g * 8192, &Ws[buf][wid * 4096 + g * 1024]); \
        } \
    } while (0)

    f32x4 acc[4][4] = {};

    PSTAGE(0, 0);
    __syncthreads();

    for (int kt = 0; kt < 8; ++kt) {
        const int cur = kt & 1;
        if (kt < 7) PSTAGE(cur ^ 1, kt + 1);
#pragma unroll
        for (int ks = 0; ks < 2; ++ks) {
            bf16x8 a[4], bb[4];
#pragma unroll
            for (int mf = 0; mf < 4; ++mf) {
                const int row = wr * 64 + mf * 16 + l15;
                a[mf] = *reinterpret_cast<const bf16x8*>(
                    &Xs[cur][row * 128 + ((ks * 64 + l4 * 16) ^ ((l15 & 7) << 4))]);
            }
#pragma unroll
            for (int nf = 0; nf < 4; ++nf) {
                const int row = wc * 64 + nf * 16 + l15;
                bb[nf] = *reinterpret_cast<const bf16x8*>(
                    &Ws[cur][row * 128 + ((ks * 64 + l4 * 16) ^ ((l15 & 7) << 4))]);
            }
#pragma unroll
            for (int mf = 0; mf < 4; ++mf)
#pragma unroll
                for (int nf = 0; nf < 4; ++nf)
                    acc[mf][nf] = mfma16(a[mf], bb[nf], acc[mf][nf]);
        }
        __syncthreads();
    }

#pragma unroll
    for (int nf = 0; nf < 4; ++nf) {
        const int col = n0 + wc * 64 + nf * 16 + l15;
#pragma unroll
        for (int mf = 0; mf < 4; ++mf) {
#pragma unroll
            for (int i = 0; i < 4; ++i) {
                const int row = m0 + wr * 64 + mf * 16 + l4 * 4 + i;
                out[(size_t)row * HID_ + col] = acc[mf][nf][i];
            }
        }
    }
}

extern "C" void kernel_launch(void* const* d_in, const int* in_sizes, int n_in,
                              void* d_out, int out_size, void* d_ws, size_t ws_size,
                              hipStream_t stream) {
    (void)in_sizes; (void)n_in; (void)out_size; (void)ws_size;
    const float* x     = (const float*)d_in[0];
    const float* bias  = (const float*)d_in[1];
    const float* w_qkv = (const float*)d_in[2];
    const float* w_out = (const float*)d_in[3];
    float* out = (float*)d_out;

    bf16* base = (bf16*)d_ws;
    bf16* Qb = base;                         // [4*8][2048][64]
    bf16* Kb = base + 4194304;               // [4*8][2048][64]
    bf16* Vt = base + 8388608;               // [4*8][64][2048] (transposed)
    bf16* AO = base + 12582912;              // [4][2048][512]; ALSO xb before attn
    bf16* xb = AO;                           // aliases AO (xb dead before attn writes)
    float* cosT = (float*)(base + 16777216); // [2048][32]
    float* sinT = cosT + 65536;
    bf16* wqb = (bf16*)(sinT + 65536);       // [1536][512]
    bf16* wob = wqb + 786432;                // [512][512]

    prep_k      <<<dim3(2560), 256, 0, stream>>>(x, w_qkv, w_out, xb, wqb, wob);
    rope_table_k<<<dim3(256), 256, 0, stream>>>(cosT, sinT);
    qkv_rope_k  <<<dim3(64, 12), 256, 0, stream>>>(xb, wqb, cosT, sinT, Qb, Kb, Vt);
    attn_k      <<<dim3(1024), 128, 0, stream>>>(Qb, Kb, Vt, bias, AO);
    proj_k      <<<dim3(64, 4), 256, 0, stream>>>(AO, wob, out);
}